// Round 6
// baseline (435.714 us; speedup 1.0000x reference)
//
#include <hip/hip_runtime.h>
#include <hip/hip_bf16.h>
#include <cstdint>
#include <cstddef>

// B=4, S=2048, D=1024, H=16, DH=64.  M = B*S = 8192.
// cast->bf16; fused QKV GEMM (MFMA, Q pre-scaled by 0.125*log2e) -> split heads;
// V transpose; MFMA flash attention: 128-q blocks, 32 q-rows/wave, S^T = K Q^T,
// no-max softmax.  Round 6: V read direct global->register (no V LDS, no V DMA
// in the barrier drain), grid (bh,qt) so XCD = bh%8 -> K/VT working set fits
// per-XCD L2, LDS 35 KB -> 4 blocks/CU via __launch_bounds__(256,4).
// Workspace: 92,274,688 B (VT aliases xb's dead region).

typedef unsigned short u16;
typedef __bf16 bf16x8 __attribute__((ext_vector_type(8)));
typedef float  f32x4  __attribute__((ext_vector_type(4)));

__device__ __forceinline__ u16 f2bf(float f) {
  unsigned u = __float_as_uint(f);
  unsigned r = u + 0x7fffu + ((u >> 16) & 1u);   // RNE
  return (u16)(r >> 16);
}

// async global->LDS, 16B per lane (dest = wave-uniform base + lane*16)
__device__ __forceinline__ void llds16(const u16* g, u16* l) {
  __builtin_amdgcn_global_load_lds(
      (const __attribute__((address_space(1))) void*)g,
      (__attribute__((address_space(3))) void*)l, 16, 0, 0);
}

// ---------------- cast fp32 -> bf16 ----------------
__global__ void cast_bf16_kernel(const float* __restrict__ in, u16* __restrict__ out, int n4) {
  int i = blockIdx.x * blockDim.x + threadIdx.x;
  if (i >= n4) return;
  float4 f = ((const float4*)in)[i];
  ushort4 u;
  u.x = f2bf(f.x); u.y = f2bf(f.y); u.z = f2bf(f.z); u.w = f2bf(f.w);
  ((ushort4*)out)[i] = u;
}

// 4 weight matrices in one launch (grid.y selects)
__global__ void cast4_kernel(const float* __restrict__ a, const float* __restrict__ b,
                             const float* __restrict__ c, const float* __restrict__ d,
                             u16* __restrict__ oa, u16* __restrict__ ob,
                             u16* __restrict__ oc, u16* __restrict__ od, int n4) {
  const int w = blockIdx.y;
  const float* src = (w == 0) ? a : (w == 1) ? b : (w == 2) ? c : d;
  u16* dst = (w == 0) ? oa : (w == 1) ? ob : (w == 2) ? oc : od;
  int i = blockIdx.x * blockDim.x + threadIdx.x;
  if (i >= n4) return;
  float4 f = ((const float4*)src)[i];
  ushort4 u;
  u.x = f2bf(f.x); u.y = f2bf(f.y); u.z = f2bf(f.z); u.w = f2bf(f.w);
  ((ushort4*)dst)[i] = u;
}

// ---------------- bf16 MFMA GEMM (m97-style), C = A*Bw^T + bias ----------------
__global__ __launch_bounds__(256) void gemm_bt(
    const u16* __restrict__ A, const u16* __restrict__ Bw,
    const float* __restrict__ b0, const float* __restrict__ b1, const float* __restrict__ b2,
    u16* __restrict__ qkv_out, float* __restrict__ flat_out,
    int K, int mode)
{
  __shared__ u16 As[128 * 32];
  __shared__ u16 Bs[128 * 32];

  const int tid = threadIdx.x;
  const int n0 = blockIdx.x * 128;
  const int m0 = blockIdx.y * 128;

  const int srow = tid >> 2;
  const int soff = (tid & 3) * 8;
  const u16* gA0 = A  + (size_t)(m0 + srow) * K + soff;
  const u16* gA1 = gA0 + (size_t)64 * K;
  const u16* gB0 = Bw + (size_t)(n0 + srow) * K + soff;
  const u16* gB1 = gB0 + (size_t)64 * K;
  u16* lA0 = As + tid * 8;
  u16* lA1 = As + 2048 + tid * 8;
  u16* lB0 = Bs + tid * 8;
  u16* lB1 = Bs + 2048 + tid * 8;

  const int lane = tid & 63;
  const int wave = tid >> 6;
  const int wm = (wave >> 1) * 64;
  const int wn = (wave & 1) * 64;
  const int fr = lane & 15;
  const int k8 = (lane >> 4) * 8;

  f32x4 zero = {0.f, 0.f, 0.f, 0.f};
  f32x4 acc[4][4];
#pragma unroll
  for (int i = 0; i < 4; i++)
#pragma unroll
    for (int j = 0; j < 4; j++) acc[i][j] = zero;

  for (int k0 = 0; k0 < K; k0 += 32) {
    llds16(gA0 + k0, lA0);
    llds16(gA1 + k0, lA1);
    llds16(gB0 + k0, lB0);
    llds16(gB1 + k0, lB1);
    __syncthreads();
    bf16x8 af[4], bfr[4];
#pragma unroll
    for (int i = 0; i < 4; i++)
      af[i] = *(const bf16x8*)(As + (wm + i * 16 + fr) * 32 + k8);
#pragma unroll
    for (int j = 0; j < 4; j++)
      bfr[j] = *(const bf16x8*)(Bs + (wn + j * 16 + fr) * 32 + k8);
#pragma unroll
    for (int i = 0; i < 4; i++)
#pragma unroll
      for (int j = 0; j < 4; j++)
        acc[i][j] = __builtin_amdgcn_mfma_f32_16x16x32_bf16(af[i], bfr[j], acc[i][j], 0, 0, 0);
    __syncthreads();
  }

  const int rbase = (lane >> 4) * 4;
  if (mode == 0) {
    const int which = n0 >> 10;
    const float* bias = (which == 0) ? b0 : ((which == 1) ? b1 : b2);
    const float post = (which == 0) ? 0.18033688011f : 1.0f;  // 0.125*log2(e)
    u16* outb = qkv_out + (size_t)which * 8388608;
#pragma unroll
    for (int j = 0; j < 4; j++) {
      const int nn = (n0 + wn + j * 16 + fr) & 1023;
      const float bb = bias[nn];
      const int h = nn >> 6, dh = nn & 63;
#pragma unroll
      for (int i = 0; i < 4; i++) {
#pragma unroll
        for (int r = 0; r < 4; r++) {
          const int m = m0 + wm + i * 16 + rbase + r;
          const int bI = m >> 11, s = m & 2047;
          outb[(((size_t)bI * 16 + h) * 2048 + s) * 64 + dh] = f2bf((acc[i][j][r] + bb) * post);
        }
      }
    }
  } else {
#pragma unroll
    for (int j = 0; j < 4; j++) {
      const int n = n0 + wn + j * 16 + fr;
      const float bb = b0[n];
#pragma unroll
      for (int i = 0; i < 4; i++) {
#pragma unroll
        for (int r = 0; r < 4; r++) {
          const int m = m0 + wm + i * 16 + rbase + r;
          flat_out[(size_t)m * 1024 + n] = acc[i][j][r] + bb;
        }
      }
    }
  }
}

// ---------------- V transpose: [BH][S][64] -> [BH][64][S] ----------------
__global__ __launch_bounds__(256) void transpose_v(const u16* __restrict__ V, u16* __restrict__ VT) {
  __shared__ u16 t_s[64 * 72];
  const int tid = threadIdx.x;
  const int st = blockIdx.x << 6;
  const int bh = blockIdx.y;
  const u16* src = V + ((size_t)bh * 2048 + st) * 64;
#pragma unroll
  for (int p = 0; p < 2; p++) {
    int i = p * 256 + tid;
    int row = i >> 3, ch = i & 7;
    bf16x8 v = *(const bf16x8*)(src + row * 64 + ch * 8);
    *(bf16x8*)(t_s + row * 72 + ch * 8) = v;
  }
  __syncthreads();
  u16* dst = VT + (size_t)bh * 131072 + st;
#pragma unroll
  for (int p = 0; p < 2; p++) {
    int i = p * 256 + tid;
    int dh = i >> 3, ch = i & 7;
    union { u16 s[8]; bf16x8 v; } u;
#pragma unroll
    for (int e = 0; e < 8; e++) u.s[e] = t_s[(ch * 8 + e) * 72 + dh];
    *(bf16x8*)(dst + (size_t)dh * 2048 + ch * 8) = u.v;
  }
}

// ---------------- MFMA flash attention: K LDS-staged, V global->register ----------------
// Grid (64 bh, 16 qt): linear block id ≡ bh (mod 8) -> XCD x serves heads
// {x, x+8, ...}; per-XCD L2 working set = 8*(K 256KB + VT 256KB) = 4 MB.
// Block 256 = 4 waves; wave owns 32 q rows (2 fragments).  Per iter: barrier
// (drains only 8 KB K DMA, L2-hit); prefetch K(jt+1); issue V(jt) frag loads
// (global b128, consumed after softmax); S^T = K Q^T; no-max softmax;
// P->LDS (wave-private); PV.
__global__ __launch_bounds__(256, 4) void attn_fa(
    const u16* __restrict__ Qb, const u16* __restrict__ Kb,
    const u16* __restrict__ VT, u16* __restrict__ Ob)
{
  __shared__ u16 k_s[2 * 4096];      // dbuf [kn][d], 16B-chunks XOR'd by row
  __shared__ u16 p_s[128 * 72];      // [q][key] bf16, stride 72 (wave-private rows)
  __shared__ float l_s[128];

  const int tid = threadIdx.x;
  const int lane = tid & 63;
  const int wave = tid >> 6;
  const int bh = blockIdx.x;
  const int qt = 15 - (int)blockIdx.y;     // big tiles first
  const size_t head = (size_t)bh << 17;
  const int fr = lane & 15;
  const int g = lane >> 4;
  const int k8 = g << 3;
  const int q0 = qt << 7;
  const int wrow = wave << 5;

  // Q fragments (pre-scaled); loop-invariant B-operands
  bf16x8 aq[2][2];
#pragma unroll
  for (int f = 0; f < 2; f++) {
    const u16* qp = Qb + head + (size_t)(q0 + wrow + (f << 4) + fr) * 64;
    aq[f][0] = *(const bf16x8*)(qp + k8);
    aq[f][1] = *(const bf16x8*)(qp + 32 + k8);
  }

  // ---- hoisted lane-constant offsets ----
  const int r0 = tid >> 3, c0 = tid & 7;
  const int r1 = 32 + r0;
  const int koff0 = r0 * 64 + (((c0 ^ r0) & 7) << 3);     // K staging src offsets
  const int koff1 = r1 * 64 + (((c0 ^ r1) & 7) << 3);
  int kaddr[4][2], voffL[4];
#pragma unroll
  for (int j = 0; j < 4; j++) {
    const int kn = (j << 4) + fr;
    kaddr[j][0] = kn * 64 + (((g ^ kn) & 7) << 3);
    kaddr[j][1] = kn * 64 + ((((g + 4) ^ kn) & 7) << 3);
    voffL[j] = kn * 2048 + k8;                            // V^T[dn] row + k-sub
  }
  u16* const prow0 = p_s + (wrow + fr) * 72;
  u16* const prow1 = p_s + (wrow + 16 + fr) * 72;
  const u16* Kbase = Kb + head;
  const u16* Vbase = VT + head;

  auto issueK = [&](int jt2, int buf) {
    const u16* Kt = Kbase + ((size_t)jt2 << 12);
    llds16(Kt + koff0, k_s + (buf << 12) + tid * 8);
    llds16(Kt + koff1, k_s + (buf << 12) + 2048 + tid * 8);
  };

  f32x4 o_acc[2][4];
  const f32x4 zero = {0.f, 0.f, 0.f, 0.f};
#pragma unroll
  for (int f = 0; f < 2; f++)
#pragma unroll
    for (int j = 0; j < 4; j++) o_acc[f][j] = zero;
  float l_run[2] = {0.f, 0.f};

  const int jmax = 2 * qt + 1;
  const int jt_diag = 2 * qt + (wave >> 1);    // per-wave diagonal tile

  issueK(0, 0);

  for (int jt = 0; jt <= jmax; jt++) {
    const int kb = jt & 1;
    __syncthreads();                       // K(jt) landed (8 KB, L2-hit)
    if (jt < jmax) issueK(jt + 1, kb ^ 1);
    if (jt > jt_diag) continue;            // wave-uniform skip (still hits barriers)
    const u16* ks = k_s + (kb << 12);

    // V(jt) fragments: global -> registers, consumed after softmax (~full-S slack)
    const u16* Vt = Vbase + (jt << 6);
    bf16x8 vf[2][4];
#pragma unroll
    for (int s2 = 0; s2 < 2; s2++)
#pragma unroll
      for (int j = 0; j < 4; j++)
        vf[s2][j] = *(const bf16x8*)(Vt + voffL[j] + (s2 << 5));

    // S^T = K Q^T for both fragments; each ka pair feeds 2 MFMAs
    f32x4 s_acc[2][4];
#pragma unroll
    for (int f = 0; f < 2; f++)
#pragma unroll
      for (int j = 0; j < 4; j++) s_acc[f][j] = zero;
#pragma unroll
    for (int j = 0; j < 4; j++) {
      const bf16x8 ka0 = *(const bf16x8*)(ks + kaddr[j][0]);
      const bf16x8 ka1 = *(const bf16x8*)(ks + kaddr[j][1]);
      s_acc[0][j] = __builtin_amdgcn_mfma_f32_16x16x32_bf16(ka0, aq[0][0], s_acc[0][j], 0, 0, 0);
      s_acc[0][j] = __builtin_amdgcn_mfma_f32_16x16x32_bf16(ka1, aq[0][1], s_acc[0][j], 0, 0, 0);
      s_acc[1][j] = __builtin_amdgcn_mfma_f32_16x16x32_bf16(ka0, aq[1][0], s_acc[1][j], 0, 0, 0);
      s_acc[1][j] = __builtin_amdgcn_mfma_f32_16x16x32_bf16(ka1, aq[1][1], s_acc[1][j], 0, 0, 0);
    }

    // no-max softmax: p = exp2(s); in-lane partial l; P -> LDS (wave-private)
    const bool dodiag = (jt == jt_diag);
#pragma unroll
    for (int f = 0; f < 2; f++) {
      const int qa = q0 + wrow + (f << 4) + fr;
      u16* prow = (f == 0) ? prow0 : prow1;
      if (dodiag) {
#pragma unroll
        for (int j = 0; j < 4; j++) {
          const int kb2 = (jt << 6) + (j << 4) + (g << 2);
          float p0 = (kb2 + 0 > qa) ? 0.f : __builtin_amdgcn_exp2f(s_acc[f][j][0]);
          float p1 = (kb2 + 1 > qa) ? 0.f : __builtin_amdgcn_exp2f(s_acc[f][j][1]);
          float p2 = (kb2 + 2 > qa) ? 0.f : __builtin_amdgcn_exp2f(s_acc[f][j][2]);
          float p3 = (kb2 + 3 > qa) ? 0.f : __builtin_amdgcn_exp2f(s_acc[f][j][3]);
          l_run[f] += (p0 + p1) + (p2 + p3);
          union { __hip_bfloat162 h; unsigned u; } ca, cb;
          ca.h = __float22bfloat162_rn(make_float2(p0, p1));
          cb.h = __float22bfloat162_rn(make_float2(p2, p3));
          *(uint2*)(prow + (j << 4) + (g << 2)) = make_uint2(ca.u, cb.u);
        }
      } else {
#pragma unroll
        for (int j = 0; j < 4; j++) {
          float p0 = __builtin_amdgcn_exp2f(s_acc[f][j][0]);
          float p1 = __builtin_amdgcn_exp2f(s_acc[f][j][1]);
          float p2 = __builtin_amdgcn_exp2f(s_acc[f][j][2]);
          float p3 = __builtin_amdgcn_exp2f(s_acc[f][j][3]);
          l_run[f] += (p0 + p1) + (p2 + p3);
          union { __hip_bfloat162 h; unsigned u; } ca, cb;
          ca.h = __float22bfloat162_rn(make_float2(p0, p1));
          cb.h = __float22bfloat162_rn(make_float2(p2, p3));
          *(uint2*)(prow + (j << 4) + (g << 2)) = make_uint2(ca.u, cb.u);
        }
      }
    }

    // O += P V   (P rows wave-private; V fragments already in registers)
#pragma unroll
    for (int s2 = 0; s2 < 2; s2++) {
      const bf16x8 ap0 = *(const bf16x8*)(prow0 + (s2 << 5) + k8);
      const bf16x8 ap1 = *(const bf16x8*)(prow1 + (s2 << 5) + k8);
#pragma unroll
      for (int j = 0; j < 4; j++) {
        o_acc[0][j] = __builtin_amdgcn_mfma_f32_16x16x32_bf16(ap0, vf[s2][j], o_acc[0][j], 0, 0, 0);
        o_acc[1][j] = __builtin_amdgcn_mfma_f32_16x16x32_bf16(ap1, vf[s2][j], o_acc[1][j], 0, 0, 0);
      }
    }
  }

  // epilogue: reduce l (q-col lives in lanes fr, fr+16, fr+32, fr+48)
#pragma unroll
  for (int f = 0; f < 2; f++) {
    float l = l_run[f];
    l += __shfl_xor(l, 16);
    l += __shfl_xor(l, 32);
    if (g == 0) l_s[wrow + (f << 4) + fr] = l;   // wave-private slot
  }
  const int b = bh >> 4, h = bh & 15;
#pragma unroll
  for (int f = 0; f < 2; f++) {
#pragma unroll
    for (int r = 0; r < 4; r++) {
      const int qloc = wrow + (f << 4) + (g << 2) + r;
      const float inv = 1.f / l_s[qloc];
      const int q_abs = q0 + qloc;
#pragma unroll
      for (int j = 0; j < 4; j++)
        Ob[((size_t)b * 2048 + q_abs) * 1024 + (h << 6) + (j << 4) + fr] =
            f2bf(o_acc[f][j][r] * inv);
    }
  }
}

// ---------------- launch ----------------
extern "C" void kernel_launch(void* const* d_in, const int* in_sizes, int n_in,
                              void* d_out, int out_size, void* d_ws, size_t ws_size,
                              hipStream_t stream) {
  const float* x  = (const float*)d_in[0];
  const float* Wq = (const float*)d_in[1];
  const float* bq = (const float*)d_in[2];
  const float* Wk = (const float*)d_in[3];
  const float* bk = (const float*)d_in[4];
  const float* Wv = (const float*)d_in[5];
  const float* bv = (const float*)d_in[6];
  const float* Wo = (const float*)d_in[7];
  const float* bo = (const float*)d_in[8];
  float* out = (float*)d_out;

  char* ws = (char*)d_ws;
  u16* xb    = (u16*)(ws);                 // 16 MB; dead after QKV GEMM
  u16* vT    = (u16*)(ws);                 // aliases xb: V^T [BH][64][S]
  u16* wqkv  = (u16*)(ws + 16777216);      // 6 MB packed q|k|v weights
  u16* wo    = (u16*)(ws + 23068672);      // 2 MB
  u16* qkv   = (u16*)(ws + 25165824);      // 48 MB, [3][BH][S][DH]
  u16* attnb = (u16*)(ws + 75497472);      // 16 MB, [B,S,D]
  // total ws: 92,274,688 B

  cast_bf16_kernel<<<8192, 256, 0, stream>>>(x, xb, 2097152);
  cast4_kernel<<<dim3(1024, 4), 256, 0, stream>>>(
      Wq, Wk, Wv, Wo, wqkv, wqkv + 1048576, wqkv + 2097152, wo, 262144);

  // fused QKV projection: M=8192, N=3072, K=1024 (Q chunk pre-scaled)
  gemm_bt<<<dim3(24, 64), 256, 0, stream>>>(xb, wqkv, bq, bk, bv, qkv, nullptr, 1024, 0);

  // V [BH][S][64] -> V^T [BH][64][S]  (xb dead; vT aliases it)
  transpose_v<<<dim3(32, 64), 256, 0, stream>>>(qkv + 16777216, vT);

  // MFMA flash attention (grid = (bh, qt) for XCD-local K/VT)
  attn_fa<<<dim3(64, 16), 256, 0, stream>>>(qkv, qkv + 8388608, vT, attnb);

  // output projection: M=8192, N=1024, K=1024 -> fp32 d_out
  gemm_bt<<<dim3(8, 64), 256, 0, stream>>>(attnb, wo, bo, bo, bo, nullptr, out, 1024, 1);
}